// Round 5
// baseline (162.595 us; speedup 1.0000x reference)
//
#include <hip/hip_runtime.h>
#include <math.h>

#define NFM_B 16384
#define NFM_F 39
#define NFM_FP 40         // padded fields (slot 39: id=0, val=0)
#define NFM_E 16
#define NFM_H 200
#define TR    8           // rows per block (MFMA M=16 tile, rows 8..15 zero)
#define KPAD  232         // padded K row stride (shorts); 464B, 16B-aligned
#define NT    13          // n-tiles of 16 (208 >= 200)

typedef short short8   __attribute__((ext_vector_type(8)));   // 8 bf16 = 4 VGPRs
typedef short short4_t __attribute__((ext_vector_type(4)));
typedef float floatx4  __attribute__((ext_vector_type(4)));

__device__ __forceinline__ short f2bf(float x) {   // fp32 -> bf16 RNE
    union { float f; unsigned u; } a; a.f = x;
    unsigned r = a.u + 0x7FFF + ((a.u >> 16) & 1);
    return (short)(r >> 16);
}
__device__ __forceinline__ float bf2f(short s) {
    union { unsigned u; float f; } a;
    a.u = ((unsigned)(unsigned short)s) << 16;
    return a.f;
}

// d_ws layout (shorts):
//   [0, VBF_SZ)            : v table converted to bf16, row-major [VOCAB][16]
//   [FRAG_OFF, +WS_FRAGS)  : W0/W1/W2 bf16 B-fragments
#define VBF_SZ   (1000000 * NFM_E)          // 16,000,000 shorts = 32 MB
#define FRAG_OFF VBF_SZ
#define W0F_OFF  0
#define W0F_SZ   (NT * 1 * 64 * 8)          // 6656
#define W1F_OFF  (W0F_OFF + W0F_SZ)
#define W1F_SZ   (NT * 7 * 64 * 8)          // 46592
#define W2F_OFF  (W1F_OFF + W1F_SZ)
#define W2F_SZ   (NT * 7 * 64 * 8)
#define WS_FRAGS (W2F_OFF + W2F_SZ)         // 99840 shorts
#define FRAG_BLOCKS ((WS_FRAGS + 255) / 256)            // 390
#define CONV_THREADS ((1000000 * NFM_E + 7) / 8)        // 2,000,000 (8 floats/thread)
#define CONV_BLOCKS ((CONV_THREADS + 255) / 256)        // 7813

// One prep kernel: blocks [0,FRAG_BLOCKS) build weight fragments; the rest
// stream-convert v (fp32->bf16). The sequential 32MB bf16 write leaves the
// table resident in the memory-side Infinity Cache for the main kernel.
__global__ __launch_bounds__(256)
void nfm_prep_kernel(const float* __restrict__ v,
                     const float* __restrict__ w0,
                     const float* __restrict__ w1,
                     const float* __restrict__ w2,
                     short* __restrict__ ws)
{
    if (blockIdx.x < FRAG_BLOCKS) {
        const int idx = blockIdx.x * 256 + threadIdx.x;
        if (idx >= WS_FRAGS) return;
        float val;
        if (idx < W1F_OFF) {
            const int rem = idx;
            const int j = rem & 7, lane = (rem >> 3) & 63, tile = rem >> 9;
            const int k = (lane >> 4) * 8 + j;
            const int n = tile * 16 + (lane & 15);
            val = (k < NFM_E && n < NFM_H) ? w0[k * NFM_H + n] : 0.f;
        } else if (idx < W2F_OFF) {
            const int rem = idx - W1F_OFF;
            const int j = rem & 7, lane = (rem >> 3) & 63;
            const int kt = rem >> 9;
            const int ks = kt % 7, tile = kt / 7;
            const int k = ks * 32 + (lane >> 4) * 8 + j;
            const int n = tile * 16 + (lane & 15);
            val = (k < NFM_H && n < NFM_H) ? w1[k * NFM_H + n] : 0.f;
        } else {
            const int rem = idx - W2F_OFF;
            const int j = rem & 7, lane = (rem >> 3) & 63;
            const int kt = rem >> 9;
            const int ks = kt % 7, tile = kt / 7;
            const int k = ks * 32 + (lane >> 4) * 8 + j;
            const int n = tile * 16 + (lane & 15);
            val = (k < NFM_H && n < NFM_H) ? w2[k * NFM_H + n] : 0.f;
        }
        ws[FRAG_OFF + idx] = f2bf(val);
    } else {
        const long t = (long)(blockIdx.x - FRAG_BLOCKS) * 256 + threadIdx.x;
        if (t >= CONV_THREADS) return;
        const long base = t * 8;
        const float4 a = *(const float4*)&v[base];
        const float4 b = *(const float4*)&v[base + 4];
        short8 o;
        o[0] = f2bf(a.x); o[1] = f2bf(a.y); o[2] = f2bf(a.z); o[3] = f2bf(a.w);
        o[4] = f2bf(b.x); o[5] = f2bf(b.y); o[6] = f2bf(b.z); o[7] = f2bf(b.w);
        *(short8*)&ws[base] = o;
    }
}

__global__ __launch_bounds__(256, 6)
void nfm_main_kernel(
    const int*   __restrict__ feat_ids,   // [B,F]
    const float* __restrict__ feat_vals,  // [B,F]
    const float* __restrict__ w,          // [VOCAB,1]
    const float* __restrict__ bglob,      // [1]
    const float* __restrict__ b0,
    const float* __restrict__ b1,
    const float* __restrict__ b2,
    const short* __restrict__ ws,         // bf16 v table + weight fragments
    float* __restrict__ out)              // [B]
{
    __shared__ __attribute__((aligned(16))) short hbfA[16 * KPAD]; // 7424 B
    __shared__ __attribute__((aligned(16))) short hbfB[16 * KPAD];
    __shared__ int   idsS [TR * NFM_FP];
    __shared__ float valsS[TR * NFM_FP];
    __shared__ float rowsumW[4][16];
    __shared__ float lrS[TR];

    const int tid  = threadIdx.x;
    const int row0 = blockIdx.x * TR;
    const int lane = tid & 63;
    const int wv   = tid >> 6;     // wave 0..3
    const int lq   = lane >> 4;    // quad 0..3
    const int ln   = lane & 15;

    const short* vbf = ws;                 // bf16 v table
    const short* Wfb = ws + FRAG_OFF;      // weight fragments

    // Zero both activation buffers (K-pad 200..231, dummy rows 8..15, fm pad).
    {
        short8 z8 = {0, 0, 0, 0, 0, 0, 0, 0};
        short8* pA = (short8*)hbfA;
        short8* pB = (short8*)hbfB;
        for (int i = tid; i < 464; i += 256) { pA[i] = z8; pB[i] = z8; }
    }
    // Stage ids/vals, padded to 40 fields (slot 39 -> id 0, val 0)
    for (int i = tid; i < TR * NFM_FP; i += 256) {
        const int r = i / NFM_FP, f = i - r * NFM_FP;
        if (f < NFM_F) {
            idsS [i] = feat_ids [(row0 + r) * NFM_F + f];
            valsS[i] = feat_vals[(row0 + r) * NFM_F + f];
        } else {
            idsS[i] = 0; valsS[i] = 0.f;
        }
    }
    __syncthreads();

    // ---------- gather + FM pooling + LR: 32 lanes per row ----------
    // lane32 = fs*4 + eg: fs (0..7) strides fields, eg (0..3) picks the
    // 8B bf16x4 slice of the 32B embedding row -> 5 independent 8B loads.
    {
        const int r8  = tid >> 5;          // 0..7
        const int l32 = tid & 31;
        const int fs  = l32 >> 2, eg = l32 & 3;
        const int*   ids = idsS  + r8 * NFM_FP;
        const float* vls = valsS + r8 * NFM_FP;

        floatx4 xv = {0.f, 0.f, 0.f, 0.f}, x2 = {0.f, 0.f, 0.f, 0.f};
#pragma unroll
        for (int it = 0; it < 5; ++it) {
            const int f = fs + it * 8;     // max 39 = pad slot
            const float val = vls[f];
            const short4_t vb = *(const short4_t*)&vbf[ids[f] * NFM_E + eg * 4];
            const float t0 = val * bf2f(vb[0]), t1 = val * bf2f(vb[1]);
            const float t2 = val * bf2f(vb[2]), t3 = val * bf2f(vb[3]);
            xv[0] += t0; xv[1] += t1; xv[2] += t2; xv[3] += t3;
            x2[0] = fmaf(t0, t0, x2[0]); x2[1] = fmaf(t1, t1, x2[1]);
            x2[2] = fmaf(t2, t2, x2[2]); x2[3] = fmaf(t3, t3, x2[3]);
        }
        // reduce over fs (xor offsets 4,8,16 within width 32)
#pragma unroll
        for (int off = 4; off <= 16; off <<= 1) {
#pragma unroll
            for (int c = 0; c < 4; ++c) {
                xv[c] += __shfl_xor(xv[c], off, 32);
                x2[c] += __shfl_xor(x2[c], off, 32);
            }
        }
        if (fs == 0) {
            short4_t fm4;
#pragma unroll
            for (int c = 0; c < 4; ++c)
                fm4[c] = f2bf(0.5f * (xv[c] * xv[c] - x2[c]));
            *(short4_t*)&hbfB[r8 * KPAD + eg * 4] = fm4;
        }
        // LR: lane covers field l32 and (padded) 32+l32
        float lr = vls[l32] * w[ids[l32]];
        if (l32 < 8) lr += vls[32 + l32] * w[ids[32 + l32]];
#pragma unroll
        for (int off = 16; off >= 1; off >>= 1)
            lr += __shfl_xor(lr, off, 32);
        if (l32 == 0) lrS[r8] = lr;
    }
    __syncthreads();

    // ---------- L0: fm(bf16, K=32) @ W0f -> hbfA ----------
    {
        const short8 af = *(const short8*)&hbfB[ln * KPAD + lq * 8];
        const short* Wf = Wfb + W0F_OFF;
        for (int t = wv; t < NT; t += 4) {
            const int n = t * 16 + ln;
            const float bj = (n < NFM_H) ? b0[n] : 0.f;
            floatx4 acc = {bj, bj, bj, bj};
            const short8 bf = *(const short8*)&Wf[(t * 64 + lane) * 8];
            acc = __builtin_amdgcn_mfma_f32_16x16x32_bf16(af, bf, acc, 0, 0, 0);
#pragma unroll
            for (int rg = 0; rg < 4; ++rg)          // n>=200 computes exact 0
                hbfA[(lq * 4 + rg) * KPAD + n] = f2bf(fmaxf(acc[rg], 0.f));
        }
    }
    __syncthreads();

    // ---------- L1: hbfA @ W1f -> hbfB ----------
    {
        short8 af[7];
#pragma unroll
        for (int ks = 0; ks < 7; ++ks)
            af[ks] = *(const short8*)&hbfA[ln * KPAD + ks * 32 + lq * 8];
        const short* Wf = Wfb + W1F_OFF;
        for (int t = wv; t < NT; t += 4) {
            const int n = t * 16 + ln;
            const float bj = (n < NFM_H) ? b1[n] : 0.f;
            floatx4 acc = {bj, bj, bj, bj};
#pragma unroll
            for (int ks = 0; ks < 7; ++ks) {
                const short8 bf = *(const short8*)&Wf[((t * 7 + ks) * 64 + lane) * 8];
                acc = __builtin_amdgcn_mfma_f32_16x16x32_bf16(af[ks], bf, acc, 0, 0, 0);
            }
#pragma unroll
            for (int rg = 0; rg < 4; ++rg)
                hbfB[(lq * 4 + rg) * KPAD + n] = f2bf(fmaxf(acc[rg], 0.f));
        }
    }
    __syncthreads();

    // ---------- L2: hbfB @ W2f -> row sums (no materialization) ----------
    {
        short8 af[7];
#pragma unroll
        for (int ks = 0; ks < 7; ++ks)
            af[ks] = *(const short8*)&hbfB[ln * KPAD + ks * 32 + lq * 8];
        const short* Wf = Wfb + W2F_OFF;
        float rs[4] = {0.f, 0.f, 0.f, 0.f};
        for (int t = wv; t < NT; t += 4) {
            const int n = t * 16 + ln;
            const float bj = (n < NFM_H) ? b2[n] : 0.f;
            floatx4 acc = {bj, bj, bj, bj};
#pragma unroll
            for (int ks = 0; ks < 7; ++ks) {
                const short8 bf = *(const short8*)&Wf[((t * 7 + ks) * 64 + lane) * 8];
                acc = __builtin_amdgcn_mfma_f32_16x16x32_bf16(af[ks], bf, acc, 0, 0, 0);
            }
#pragma unroll
            for (int rg = 0; rg < 4; ++rg)
                rs[rg] += fmaxf(acc[rg], 0.f);       // n>=200 adds exact 0
        }
#pragma unroll
        for (int off = 8; off >= 1; off >>= 1)
#pragma unroll
            for (int rg = 0; rg < 4; ++rg)
                rs[rg] += __shfl_xor(rs[rg], off, 16);
        if (ln == 0)
#pragma unroll
            for (int rg = 0; rg < 4; ++rg)
                rowsumW[wv][lq * 4 + rg] = rs[rg];
    }
    __syncthreads();

    // ---------- epilogue (rows 0..7 are real) ----------
    if (tid < TR) {
        const float s = rowsumW[0][tid] + rowsumW[1][tid]
                      + rowsumW[2][tid] + rowsumW[3][tid];
        const float logit = lrS[tid] + bglob[0] + s;
        out[row0 + tid] = 1.f / (1.f + expf(-logit));
    }
}

extern "C" void kernel_launch(void* const* d_in, const int* in_sizes, int n_in,
                              void* d_out, int out_size, void* d_ws, size_t ws_size,
                              hipStream_t stream) {
    const int*   feat_ids  = (const int*)  d_in[0];
    const float* feat_vals = (const float*)d_in[1];
    const float* w   = (const float*)d_in[2];
    const float* v   = (const float*)d_in[3];
    const float* b   = (const float*)d_in[4];
    const float* w0  = (const float*)d_in[5];
    const float* b0  = (const float*)d_in[6];
    const float* w1  = (const float*)d_in[7];
    const float* b1  = (const float*)d_in[8];
    const float* w2  = (const float*)d_in[9];
    const float* b2  = (const float*)d_in[10];
    float* out = (float*)d_out;
    short* ws  = (short*)d_ws;   // needs (16,000,000 + 99,840) * 2 B ~= 32.2 MB

    hipLaunchKernelGGL(nfm_prep_kernel, dim3(FRAG_BLOCKS + CONV_BLOCKS), dim3(256),
                       0, stream, v, w0, w1, w2, ws);
    hipLaunchKernelGGL(nfm_main_kernel, dim3(NFM_B / TR), dim3(256), 0, stream,
                       feat_ids, feat_vals, w, b, b0, b1, b2, ws, out);
}

// Round 6
// 139.955 us; speedup vs baseline: 1.1618x; 1.1618x over previous
//
#include <hip/hip_runtime.h>
#include <math.h>

#define NFM_B 16384
#define NFM_F 39
#define NFM_E 16
#define NFM_H 200
#define TR    8           // rows per block (MFMA M=16 tile, rows 8..15 zero)
#define KPAD  232         // padded K row stride (shorts); 464B, 16B-aligned
#define NT    13          // n-tiles of 16 (208 >= 200)
#define VOCAB 1000000

typedef short short8   __attribute__((ext_vector_type(8)));   // 8 bf16 = 4 VGPRs
typedef short short4_t __attribute__((ext_vector_type(4)));
typedef float floatx4  __attribute__((ext_vector_type(4)));

__device__ __forceinline__ short f2bf(float x) {   // fp32 -> bf16 RNE
    union { float f; unsigned u; } a; a.f = x;
    unsigned r = a.u + 0x7FFF + ((a.u >> 16) & 1);
    return (short)(r >> 16);
}
__device__ __forceinline__ float bf2f(short s) {
    union { unsigned u; float f; } a;
    a.u = ((unsigned)(unsigned short)s) << 16;
    return a.f;
}

// d_ws layout (shorts):
//   [0, VOCAB)             : w table converted to bf16 (2 MB, L2-resident)
//   [FRAG_OFF, +WS_FRAGS)  : W0/W1/W2 bf16 B-fragments
#define WBF_SZ   VOCAB
#define FRAG_OFF WBF_SZ                     // 1,000,000 shorts -> 2 MB (16B-aligned)
#define W0F_OFF  0
#define W0F_SZ   (NT * 1 * 64 * 8)          // 6656
#define W1F_OFF  (W0F_OFF + W0F_SZ)
#define W1F_SZ   (NT * 7 * 64 * 8)          // 46592
#define W2F_OFF  (W1F_OFF + W1F_SZ)
#define W2F_SZ   (NT * 7 * 64 * 8)
#define WS_FRAGS (W2F_OFF + W2F_SZ)         // 99840 shorts
#define FRAG_BLOCKS  ((WS_FRAGS + 255) / 256)           // 390
#define WCONV_THREADS (VOCAB / 8)                       // 125,000 (8 floats/thread)
#define WCONV_BLOCKS ((WCONV_THREADS + 255) / 256)      // 489

// Prep: blocks [0,FRAG_BLOCKS) build weight fragments; rest convert w->bf16.
// Total ~6 MB of traffic (~2 us) -- v is NOT converted (R5 showed no benefit).
__global__ __launch_bounds__(256)
void nfm_prep_kernel(const float* __restrict__ w,
                     const float* __restrict__ w0,
                     const float* __restrict__ w1,
                     const float* __restrict__ w2,
                     short* __restrict__ ws)
{
    if (blockIdx.x < FRAG_BLOCKS) {
        const int idx = blockIdx.x * 256 + threadIdx.x;
        if (idx >= WS_FRAGS) return;
        float val;
        if (idx < W1F_OFF) {
            const int rem = idx;
            const int j = rem & 7, lane = (rem >> 3) & 63, tile = rem >> 9;
            const int k = (lane >> 4) * 8 + j;
            const int n = tile * 16 + (lane & 15);
            val = (k < NFM_E && n < NFM_H) ? w0[k * NFM_H + n] : 0.f;
        } else if (idx < W2F_OFF) {
            const int rem = idx - W1F_OFF;
            const int j = rem & 7, lane = (rem >> 3) & 63;
            const int kt = rem >> 9;
            const int ks = kt % 7, tile = kt / 7;
            const int k = ks * 32 + (lane >> 4) * 8 + j;
            const int n = tile * 16 + (lane & 15);
            val = (k < NFM_H && n < NFM_H) ? w1[k * NFM_H + n] : 0.f;
        } else {
            const int rem = idx - W2F_OFF;
            const int j = rem & 7, lane = (rem >> 3) & 63;
            const int kt = rem >> 9;
            const int ks = kt % 7, tile = kt / 7;
            const int k = ks * 32 + (lane >> 4) * 8 + j;
            const int n = tile * 16 + (lane & 15);
            val = (k < NFM_H && n < NFM_H) ? w2[k * NFM_H + n] : 0.f;
        }
        ws[FRAG_OFF + idx] = f2bf(val);
    } else {
        const int t = (blockIdx.x - FRAG_BLOCKS) * 256 + threadIdx.x;
        if (t >= WCONV_THREADS) return;
        const int base = t * 8;
        const float4 a = *(const float4*)&w[base];
        const float4 b = *(const float4*)&w[base + 4];
        short8 o;
        o[0] = f2bf(a.x); o[1] = f2bf(a.y); o[2] = f2bf(a.z); o[3] = f2bf(a.w);
        o[4] = f2bf(b.x); o[5] = f2bf(b.y); o[6] = f2bf(b.z); o[7] = f2bf(b.w);
        *(short8*)&ws[base] = o;
    }
}

__global__ __launch_bounds__(256, 8)
void nfm_main_kernel(
    const int*   __restrict__ feat_ids,   // [B,F]
    const float* __restrict__ feat_vals,  // [B,F]
    const float* __restrict__ v,          // [VOCAB,16] fp32
    const float* __restrict__ bglob,      // [1]
    const float* __restrict__ b0,
    const float* __restrict__ b1,
    const float* __restrict__ b2,
    const short* __restrict__ ws,         // bf16 w table + weight fragments
    float* __restrict__ out)              // [B]
{
    __shared__ __attribute__((aligned(16))) short hbfA[16 * KPAD]; // 7424 B
    __shared__ __attribute__((aligned(16))) short hbfB[16 * KPAD];
    __shared__ float rowsumW[4][16];
    __shared__ float lrS[TR];

    const int tid  = threadIdx.x;
    const int row0 = blockIdx.x * TR;
    const int lane = tid & 63;
    const int wv   = tid >> 6;     // wave 0..3
    const int lq   = lane >> 4;    // quad 0..3
    const int ln   = lane & 15;

    const short* wbf = ws;                 // bf16 w table
    const short* Wfb = ws + FRAG_OFF;      // weight fragments

    // ---------- issue all gather loads up front (latency overlapped by
    // the LDS zero-fill below; no staging barrier in the way) ----------
    const int r8  = tid >> 5;              // 0..7 row within block
    const int l32 = tid & 31;
    const int fs  = l32 >> 2, eg = l32 & 3;
    const long rbase = (long)(row0 + r8) * NFM_F;

    int   idv[5]; float vlv[5];
#pragma unroll
    for (int it = 0; it < 5; ++it) {
        const int f = fs + it * 8;         // fs=7,it=4 -> 39 OOB
        const bool ok = f < NFM_F;
        idv[it] = ok ? feat_ids [rbase + f] : 0;
        vlv[it] = ok ? feat_vals[rbase + f] : 0.f;
    }
    float4 ve[5];
#pragma unroll
    for (int it = 0; it < 5; ++it)
        ve[it] = *(const float4*)&v[(long)idv[it] * NFM_E + eg * 4];

    const int   idw1 = feat_ids [rbase + l32];           // l32 < 39 always
    const float vw1  = feat_vals[rbase + l32];
    const int   idw2 = (l32 < 7) ? feat_ids [rbase + 32 + l32] : 0;
    const float vw2  = (l32 < 7) ? feat_vals[rbase + 32 + l32] : 0.f;
    const float wv1  = bf2f(wbf[idw1]);
    const float wv2  = bf2f(wbf[idw2]);

    // Zero both activation buffers (K-pad 200..231, dummy rows 8..15, fm pad
    // cols 16..31) while the gather loads are in flight.
    {
        short8 z8 = {0, 0, 0, 0, 0, 0, 0, 0};
        short8* pA = (short8*)hbfA;
        short8* pB = (short8*)hbfB;
        for (int i = tid; i < 464; i += 256) { pA[i] = z8; pB[i] = z8; }
    }
    __syncthreads();   // zero-fill visible before fm stores land

    // ---------- FM pooling + LR ----------
    {
        floatx4 xv = {0.f, 0.f, 0.f, 0.f}, x2 = {0.f, 0.f, 0.f, 0.f};
#pragma unroll
        for (int it = 0; it < 5; ++it) {
            const float val = vlv[it];
            const float t0 = val * ve[it].x, t1 = val * ve[it].y;
            const float t2 = val * ve[it].z, t3 = val * ve[it].w;
            xv[0] += t0; xv[1] += t1; xv[2] += t2; xv[3] += t3;
            x2[0] = fmaf(t0, t0, x2[0]); x2[1] = fmaf(t1, t1, x2[1]);
            x2[2] = fmaf(t2, t2, x2[2]); x2[3] = fmaf(t3, t3, x2[3]);
        }
#pragma unroll
        for (int off = 4; off <= 16; off <<= 1) {
#pragma unroll
            for (int c = 0; c < 4; ++c) {
                xv[c] += __shfl_xor(xv[c], off, 32);
                x2[c] += __shfl_xor(x2[c], off, 32);
            }
        }
        if (fs == 0) {
            short4_t fm4;
#pragma unroll
            for (int c = 0; c < 4; ++c)
                fm4[c] = f2bf(0.5f * (xv[c] * xv[c] - x2[c]));
            *(short4_t*)&hbfB[r8 * KPAD + eg * 4] = fm4;
        }
        float lr = vw1 * wv1 + vw2 * wv2;
#pragma unroll
        for (int off = 16; off >= 1; off >>= 1)
            lr += __shfl_xor(lr, off, 32);
        if (l32 == 0) lrS[r8] = lr;
    }
    __syncthreads();

    // ---------- L0: fm(bf16, K=32) @ W0f -> hbfA ----------
    {
        const short8 af = *(const short8*)&hbfB[ln * KPAD + lq * 8];
        const short* Wf = Wfb + W0F_OFF;
        for (int t = wv; t < NT; t += 4) {
            const int n = t * 16 + ln;
            const float bj = (n < NFM_H) ? b0[n] : 0.f;
            floatx4 acc = {bj, bj, bj, bj};
            const short8 bf = *(const short8*)&Wf[(t * 64 + lane) * 8];
            acc = __builtin_amdgcn_mfma_f32_16x16x32_bf16(af, bf, acc, 0, 0, 0);
#pragma unroll
            for (int rg = 0; rg < 4; ++rg)          // n>=200 computes exact 0
                hbfA[(lq * 4 + rg) * KPAD + n] = f2bf(fmaxf(acc[rg], 0.f));
        }
    }
    __syncthreads();

    // ---------- L1: hbfA @ W1f -> hbfB ----------
    {
        short8 af[7];
#pragma unroll
        for (int ks = 0; ks < 7; ++ks)
            af[ks] = *(const short8*)&hbfA[ln * KPAD + ks * 32 + lq * 8];
        const short* Wf = Wfb + W1F_OFF;
        for (int t = wv; t < NT; t += 4) {
            const int n = t * 16 + ln;
            const float bj = (n < NFM_H) ? b1[n] : 0.f;
            floatx4 acc = {bj, bj, bj, bj};
#pragma unroll
            for (int ks = 0; ks < 7; ++ks) {
                const short8 bf = *(const short8*)&Wf[((t * 7 + ks) * 64 + lane) * 8];
                acc = __builtin_amdgcn_mfma_f32_16x16x32_bf16(af[ks], bf, acc, 0, 0, 0);
            }
#pragma unroll
            for (int rg = 0; rg < 4; ++rg)
                hbfB[(lq * 4 + rg) * KPAD + n] = f2bf(fmaxf(acc[rg], 0.f));
        }
    }
    __syncthreads();

    // ---------- L2: hbfB @ W2f -> row sums (no materialization) ----------
    {
        short8 af[7];
#pragma unroll
        for (int ks = 0; ks < 7; ++ks)
            af[ks] = *(const short8*)&hbfB[ln * KPAD + ks * 32 + lq * 8];
        const short* Wf = Wfb + W2F_OFF;
        float rs[4] = {0.f, 0.f, 0.f, 0.f};
        for (int t = wv; t < NT; t += 4) {
            const int n = t * 16 + ln;
            const float bj = (n < NFM_H) ? b2[n] : 0.f;
            floatx4 acc = {bj, bj, bj, bj};
#pragma unroll
            for (int ks = 0; ks < 7; ++ks) {
                const short8 bf = *(const short8*)&Wf[((t * 7 + ks) * 64 + lane) * 8];
                acc = __builtin_amdgcn_mfma_f32_16x16x32_bf16(af[ks], bf, acc, 0, 0, 0);
            }
#pragma unroll
            for (int rg = 0; rg < 4; ++rg)
                rs[rg] += fmaxf(acc[rg], 0.f);       // n>=200 adds exact 0
        }
#pragma unroll
        for (int off = 8; off >= 1; off >>= 1)
#pragma unroll
            for (int rg = 0; rg < 4; ++rg)
                rs[rg] += __shfl_xor(rs[rg], off, 16);
        if (ln == 0)
#pragma unroll
            for (int rg = 0; rg < 4; ++rg)
                rowsumW[wv][lq * 4 + rg] = rs[rg];
    }
    __syncthreads();

    // ---------- epilogue (rows 0..7 are real) ----------
    if (tid < TR) {
        const float s = rowsumW[0][tid] + rowsumW[1][tid]
                      + rowsumW[2][tid] + rowsumW[3][tid];
        const float logit = lrS[tid] + bglob[0] + s;
        out[row0 + tid] = 1.f / (1.f + expf(-logit));
    }
}

extern "C" void kernel_launch(void* const* d_in, const int* in_sizes, int n_in,
                              void* d_out, int out_size, void* d_ws, size_t ws_size,
                              hipStream_t stream) {
    const int*   feat_ids  = (const int*)  d_in[0];
    const float* feat_vals = (const float*)d_in[1];
    const float* w   = (const float*)d_in[2];
    const float* v   = (const float*)d_in[3];
    const float* b   = (const float*)d_in[4];
    const float* w0  = (const float*)d_in[5];
    const float* b0  = (const float*)d_in[6];
    const float* w1  = (const float*)d_in[7];
    const float* b1  = (const float*)d_in[8];
    const float* w2  = (const float*)d_in[9];
    const float* b2  = (const float*)d_in[10];
    float* out = (float*)d_out;
    short* ws  = (short*)d_ws;   // needs (1,000,000 + 99,840) * 2 B ~= 2.2 MB

    hipLaunchKernelGGL(nfm_prep_kernel, dim3(FRAG_BLOCKS + WCONV_BLOCKS), dim3(256),
                       0, stream, w, w0, w1, w2, ws);
    hipLaunchKernelGGL(nfm_main_kernel, dim3(NFM_B / TR), dim3(256), 0, stream,
                       feat_ids, feat_vals, v, b, b0, b1, b2, ws, out);
}